// Round 5
// baseline (764.522 us; speedup 1.0000x reference)
//
#include <hip/hip_runtime.h>
#include <hip/hip_bf16.h>

// GCN: h1 = relu(Â (x W1) + b1); h2 = relu(Â (h1 W2) + b2);
// out = mean_pool(h2, batch) @ Wlin + blin,  Â = D^-1/2 (A+I) D^-1/2
//
// R2: per-graph counts via sorted-batch boundaries (was 508 us of atomics).
// R3: norm folded into gemm epilogue (xws = dinv*xw); agg unrolled x4.
// R5: bucketed CSR build. Old fill_k scattered 4 B stores across 6.4 MB ->
//     105 MB HBM writeback (64 B/line per store). Now: bin edges by 128-node
//     dst range (packed 4 B records), then one block per bucket builds its
//     dst-ordered CSR slice with LDS hist/scan + L2-local scatter (one XCD
//     owns each 8 KB region -> ~16 writes/line before writeback).
//     count_k/alloc_k/degi deleted; agg uses start[v+1]-start[v].

#define NDIM 64
#define NGRAPH 64
#define BSHIFT 7                      // 128 nodes per bucket
#define BNODES 128

// ---- pass 1: per-bucket edge counts (LDS histogram) ----
__global__ void bincnt_k(const int* __restrict__ dst, int* __restrict__ bucketCnt,
                         int e, int nb) {
    extern __shared__ int hist[];
    int t = threadIdx.x;
    for (int i = t; i < nb; i += 256) hist[i] = 0;
    __syncthreads();
    int base = blockIdx.x * 2048 + t;
#pragma unroll
    for (int k = 0; k < 8; ++k) {
        int i = base + k * 256;
        if (i < e) atomicAdd(&hist[dst[i] >> BSHIFT], 1);
    }
    __syncthreads();
    for (int i = t; i < nb; i += 256) {
        int c = hist[i];
        if (c) atomicAdd(&bucketCnt[i], c);
    }
}

// ---- pass 2: exclusive scan of bucket counts (single block, nb<=1024) ----
__global__ void bscan_k(const int* __restrict__ bucketCnt, int* __restrict__ bucketStart,
                        int* __restrict__ bucketCursor, int* __restrict__ start,
                        int nb, int n, int e) {
    __shared__ int s[1024];
    int t = threadIdx.x;
    int v = (t < nb) ? bucketCnt[t] : 0;
    s[t] = v;
    __syncthreads();
    for (int off = 1; off < 1024; off <<= 1) {
        int tmp = (t >= off) ? s[t - off] : 0;
        __syncthreads();
        s[t] += tmp;
        __syncthreads();
    }
    if (t < nb) {
        bucketStart[t + 1] = s[t];
        bucketCursor[t] = s[t] - v;       // exclusive
    }
    if (t == 0) { bucketStart[0] = 0; start[n] = e; }  // CSR sentinel
}

// ---- pass 3: scatter packed (dst_local<<25 | src) into bucket regions ----
__global__ void bscatter_k(const int* __restrict__ src, const int* __restrict__ dst,
                           int* __restrict__ cursor, unsigned int* __restrict__ ebuf,
                           int e) {
    int base = blockIdx.x * 2048 + threadIdx.x;
#pragma unroll
    for (int k = 0; k < 8; ++k) {
        int i = base + k * 256;
        if (i < e) {
            int d = dst[i];
            int b = d >> BSHIFT;
            int pos = atomicAdd(&cursor[b], 1);
            ebuf[pos] = ((unsigned)(d & (BNODES - 1)) << 25) | (unsigned)src[i];
        }
    }
}

// ---- pass 4: one block per bucket -> dst-ordered CSR slice, dinv, ranges ----
__global__ void fill2_k(const unsigned int* __restrict__ ebuf,
                        const int* __restrict__ bucketStart,
                        const int* __restrict__ batch, float* __restrict__ dinv,
                        int* __restrict__ start, int* __restrict__ csr,
                        int* __restrict__ gstart, int* __restrict__ gend, int n) {
    __shared__ int scnt[BNODES], sincl[BNODES], scur[BNODES];
    int t = threadIdx.x;
    int b = blockIdx.x;
    int node0 = b << BSHIFT;
    int nNodes = min(BNODES, n - node0);
    if (t < BNODES) scnt[t] = 0;
    int e0 = bucketStart[b], e1 = bucketStart[b + 1];
    __syncthreads();
    for (int i = e0 + t; i < e1; i += 256)
        atomicAdd(&scnt[ebuf[i] >> 25], 1);
    __syncthreads();
    int val = (t < BNODES) ? scnt[t] : 0;
    if (t < BNODES) sincl[t] = val;
    __syncthreads();
    for (int off = 1; off < BNODES; off <<= 1) {
        int tmp = (t >= off && t < BNODES) ? sincl[t - off] : 0;
        __syncthreads();
        if (t < BNODES) sincl[t] += tmp;
        __syncthreads();
    }
    if (t < nNodes) {
        int v = node0 + t;
        int st = e0 + sincl[t] - val;     // exclusive within bucket
        start[v] = st;
        scur[t] = st;
        dinv[v] = rsqrtf((float)(val + 1));
        int g = batch[v];                 // sorted-batch boundary detection
        if (v == 0 || batch[v - 1] != g) gstart[g] = v;
        if (v == n - 1 || batch[v + 1] != g) gend[g] = v + 1;
    }
    __syncthreads();
    for (int i = e0 + t; i < e1; i += 256) {
        unsigned rec = ebuf[i];
        int pos = atomicAdd(&scur[rec >> 25], 1);
        csr[pos] = (int)(rec & 0x1FFFFFFu);   // scatter within L2-local 8 KB slice
    }
}

// ---- dense GEMM  C[n,64] = scale[row] * (A[n,64] @ W[64,64]) ----
__global__ void gemm_k(const float* __restrict__ A, const float* __restrict__ W,
                       const float* __restrict__ scale, float* __restrict__ C, int n) {
    __shared__ float Wl[64 * 64];
    __shared__ float Xl[256];
    int t = threadIdx.x;
#pragma unroll
    for (int i = 0; i < 16; ++i) Wl[t + 256 * i] = W[t + 256 * i];
    long base = (long)blockIdx.x * 256;
    Xl[t] = (base + t < (long)n * NDIM) ? A[base + t] : 0.f;
    __syncthreads();
    int row = t >> 6, col = t & 63;
    float acc = 0.f;
    const float4* Xv = (const float4*)&Xl[row * 64];
#pragma unroll
    for (int k4 = 0; k4 < 16; ++k4) {
        float4 xv = Xv[k4];
        acc += xv.x * Wl[(4 * k4 + 0) * 64 + col];
        acc += xv.y * Wl[(4 * k4 + 1) * 64 + col];
        acc += xv.z * Wl[(4 * k4 + 2) * 64 + col];
        acc += xv.w * Wl[(4 * k4 + 3) * 64 + col];
    }
    int v = blockIdx.x * 4 + row;
    if (v < n) C[(long)v * NDIM + col] = scale[v] * acc;
}

// ---- aggregation: out[v,:] = relu( dinv[v]*(sum_e xws[src_e,:] + xws[v,:]) + b ) ----
// one 64-lane wave per node, lane = dim; unrolled x4 -> 4 gathers in flight
__global__ void agg_k(const float* __restrict__ xws, const float* __restrict__ dinv,
                      const int* __restrict__ start, const int* __restrict__ csr,
                      const float* __restrict__ bias, float* __restrict__ out, int n) {
    int t = threadIdx.x;
    int lane = t & 63;
    int v = blockIdx.x * 4 + (t >> 6);
    if (v >= n) return;
    int s0 = start[v];
    int d0 = start[v + 1] - s0;
    float a0 = 0.f, a1 = 0.f, a2 = 0.f, a3 = 0.f;
    int i = 0;
    for (; i + 4 <= d0; i += 4) {
        int j0 = csr[s0 + i + 0];
        int j1 = csr[s0 + i + 1];
        int j2 = csr[s0 + i + 2];
        int j3 = csr[s0 + i + 3];
        float x0 = xws[(long)j0 * NDIM + lane];
        float x1 = xws[(long)j1 * NDIM + lane];
        float x2 = xws[(long)j2 * NDIM + lane];
        float x3 = xws[(long)j3 * NDIM + lane];
        a0 += x0; a1 += x1; a2 += x2; a3 += x3;
    }
    for (; i < d0; ++i) a0 += xws[(long)csr[s0 + i] * NDIM + lane];
    float acc = (a0 + a1) + (a2 + a3);
    acc += xws[(long)v * NDIM + lane];          // self loop (xws already has one dinv)
    acc = acc * dinv[v] + bias[lane];
    out[(long)v * NDIM + lane] = fmaxf(acc, 0.f);
}

// ---- mean-pool (batch sorted): register accumulate, flush on graph change ----
#define POOL_TILE 256
__global__ void pool_k(const float* __restrict__ h, const int* __restrict__ batch,
                       float* __restrict__ pooled, int n) {
    int t = threadIdx.x;
    int lane = t & 63;
    int sub = t >> 6;                 // 0..3
    int base = blockIdx.x * POOL_TILE;
    int gcur = -1;
    float acc = 0.f;
    for (int k = 0; k < POOL_TILE / 4; ++k) {
        int v = base + sub + 4 * k;   // monotone per thread -> few graph changes
        if (v < n) {
            int g = batch[v];
            if (g != gcur) {
                if (gcur >= 0) atomicAdd(&pooled[gcur * NDIM + lane], acc);
                gcur = g;
                acc = 0.f;
            }
            acc += h[(long)v * NDIM + lane];
        }
    }
    if (gcur >= 0) atomicAdd(&pooled[gcur * NDIM + lane], acc);
}

// ---- head: out[g,c] = (pooled[g,:]/max(cnt,1)) @ Wlin + blin ----
__global__ void final_k(const float* __restrict__ pooled, const int* __restrict__ gstart,
                        const int* __restrict__ gend,
                        const float* __restrict__ Wlin, const float* __restrict__ blin,
                        float* __restrict__ out, int nclass) {
    int t = blockIdx.x * blockDim.x + threadIdx.x;
    if (t >= NGRAPH * nclass) return;
    int g = t / nclass, c = t % nclass;
    float cnt = (float)(gend[g] - gstart[g]);
    float inv = 1.f / fmaxf(cnt, 1.f);
    float acc = 0.f;
    for (int j = 0; j < NDIM; ++j) acc += pooled[g * NDIM + j] * Wlin[j * nclass + c];
    out[t] = acc * inv + blin[c];
}

extern "C" void kernel_launch(void* const* d_in, const int* in_sizes, int n_in,
                              void* d_out, int out_size, void* d_ws, size_t ws_size,
                              hipStream_t stream) {
    const float* x     = (const float*)d_in[0];
    const int*   ei    = (const int*)d_in[1];
    const int*   batch = (const int*)d_in[2];
    const float* W1    = (const float*)d_in[3];
    const float* b1    = (const float*)d_in[4];
    const float* W2    = (const float*)d_in[5];
    const float* b2    = (const float*)d_in[6];
    const float* Wlin  = (const float*)d_in[7];
    const float* blin  = (const float*)d_in[8];
    float* out = (float*)d_out;

    const int N = in_sizes[0] / NDIM;        // 100000
    const int E = in_sizes[1] / 2;           // 1600000
    const int NCLASS = in_sizes[7] / NDIM;   // 10
    const int* src = ei;
    const int* dst = ei + E;
    const int NB = (N + BNODES - 1) >> BSHIFT;   // 782 buckets (<=1024 for bscan)

    // ---- workspace carve-out (each 256B-aligned) ----
    size_t o = 0;
    char* wsp = (char*)d_ws;
    auto take = [&](size_t nbytes) -> void* {
        void* p = (void*)(wsp + o);
        o += (nbytes + 255) & ~(size_t)255;
        return p;
    };
    int*   bucketCnt = (int*)take((size_t)NB * 4);
    int*   gstart    = (int*)take(NGRAPH * 4);
    int*   gend      = (int*)take(NGRAPH * 4);
    float* pooled    = (float*)take(NGRAPH * NDIM * 4);
    size_t zero_bytes = o;                    // everything above must start at 0
    int*   bucketStart  = (int*)take((size_t)(NB + 1) * 4);
    int*   bucketCursor = (int*)take((size_t)NB * 4);
    float* dinv  = (float*)take((size_t)N * 4);
    int*   start = (int*)take((size_t)(N + 1) * 4);
    int*   csr   = (int*)take((size_t)E * 4);
    unsigned int* ebuf = (unsigned int*)take((size_t)E * 4);
    float* xws   = (float*)take((size_t)N * NDIM * 4);
    float* h     = (float*)take((size_t)N * NDIM * 4);
    (void)ws_size;

    hipMemsetAsync(d_ws, 0, zero_bytes, stream);

    int ebl8 = (E + 2047) / 2048;             // 8 edges/thread
    int rbl  = (N + 3) / 4;                   // 4 nodes per block (gemm/agg)

    // CSR build (bucketed)
    bincnt_k<<<ebl8, 256, (size_t)NB * 4, stream>>>(dst, bucketCnt, E, NB);
    bscan_k<<<1, 1024, 0, stream>>>(bucketCnt, bucketStart, bucketCursor, start, NB, N, E);
    bscatter_k<<<ebl8, 256, 0, stream>>>(src, dst, bucketCursor, ebuf, E);
    fill2_k<<<NB, 256, 0, stream>>>(ebuf, bucketStart, batch, dinv, start, csr, gstart, gend, N);

    // layer 1
    gemm_k<<<rbl, 256, 0, stream>>>(x, W1, dinv, xws, N);
    agg_k<<<rbl, 256, 0, stream>>>(xws, dinv, start, csr, b1, h, N);
    // layer 2
    gemm_k<<<rbl, 256, 0, stream>>>(h, W2, dinv, xws, N);
    agg_k<<<rbl, 256, 0, stream>>>(xws, dinv, start, csr, b2, h, N);

    // pooling + head
    pool_k<<<(N + POOL_TILE - 1) / POOL_TILE, 256, 0, stream>>>(h, batch, pooled, N);
    final_k<<<(NGRAPH * NCLASS + 255) / 256, 256, 0, stream>>>(pooled, gstart, gend, Wlin, blin, out, NCLASS);
}

// Round 6
// 403.479 us; speedup vs baseline: 1.8948x; 1.8948x over previous
//
#include <hip/hip_runtime.h>
#include <hip/hip_bf16.h>

// GCN: h1 = relu(Â (x W1) + b1); h2 = relu(Â (h1 W2) + b2);
// out = mean_pool(h2, batch) @ Wlin + blin,  Â = D^-1/2 (A+I) D^-1/2
//
// R2: per-graph counts via sorted-batch boundaries (was 508 us of atomics).
// R3: norm folded into gemm epilogue (xws = dinv*xw); agg unrolled x4.
// R5: bucketed CSR build (bucket = 128-node dst range).
// R6: R5's bscatter had 1.6M returning atomics over 782 cursors -> 2048-deep
//     same-address chains @ ~180ns = 378 us. Now deterministic two-pass:
//     per-block LDS histograms -> cntmat[blk][b], column scans -> exact base
//     per (block,bucket), scatter with block-private LDS cursors.
//     ZERO global atomics in the whole pipeline.

#define NDIM 64
#define NGRAPH 64
#define BSHIFT 7                      // 128 nodes per bucket
#define BNODES 128
#define ECHUNK 8192                   // edges per block in bincnt/bscatter (32/thread)

// ---- pass 1: per-(block,bucket) edge counts via LDS histogram ----
__global__ void bincnt_k(const int* __restrict__ dst, int* __restrict__ cntmat,
                         int e, int nb) {
    extern __shared__ int hist[];
    int t = threadIdx.x;
    for (int i = t; i < nb; i += 256) hist[i] = 0;
    __syncthreads();
    int base = blockIdx.x * ECHUNK + t;
#pragma unroll
    for (int k = 0; k < 32; ++k) {
        int i = base + k * 256;
        if (i < e) atomicAdd(&hist[dst[i] >> BSHIFT], 1);   // LDS atomic
    }
    __syncthreads();
    long row = (long)blockIdx.x * nb;
    for (int i = t; i < nb; i += 256) cntmat[row + i] = hist[i];
}

// ---- pass 2: per-bucket exclusive scan across blocks (one block per bucket) ----
// requires nblk <= 256
__global__ void colscan_k(const int* __restrict__ cntmat, int* __restrict__ basemat,
                          int* __restrict__ bucketTot, int nblk, int nb) {
    __shared__ int s[256];
    int b = blockIdx.x;
    int t = threadIdx.x;
    int v = (t < nblk) ? cntmat[(long)t * nb + b] : 0;
    s[t] = v;
    __syncthreads();
    for (int off = 1; off < 256; off <<= 1) {
        int tmp = (t >= off) ? s[t - off] : 0;
        __syncthreads();
        s[t] += tmp;
        __syncthreads();
    }
    if (t < nblk) basemat[(long)t * nb + b] = s[t] - v;   // exclusive within column
    if (t == 255) bucketTot[b] = s[255];
}

// ---- pass 3: exclusive scan of bucket totals (single block, nb<=1024) ----
__global__ void bscan_k(const int* __restrict__ bucketTot, int* __restrict__ bucketStart,
                        int* __restrict__ start, int nb, int n, int e) {
    __shared__ int s[1024];
    int t = threadIdx.x;
    int v = (t < nb) ? bucketTot[t] : 0;
    s[t] = v;
    __syncthreads();
    for (int off = 1; off < 1024; off <<= 1) {
        int tmp = (t >= off) ? s[t - off] : 0;
        __syncthreads();
        s[t] += tmp;
        __syncthreads();
    }
    if (t < nb) bucketStart[t + 1] = s[t];
    if (t == 0) { bucketStart[0] = 0; start[n] = e; }   // CSR sentinel
}

// ---- pass 4: scatter packed (dst_local<<25 | src) via block-private LDS cursors ----
// MUST use the same edge->block assignment as bincnt_k.
__global__ void bscatter_k(const int* __restrict__ src, const int* __restrict__ dst,
                           const int* __restrict__ bucketStart,
                           const int* __restrict__ basemat,
                           unsigned int* __restrict__ ebuf, int e, int nb) {
    extern __shared__ int cur[];
    int t = threadIdx.x;
    long row = (long)blockIdx.x * nb;
    for (int i = t; i < nb; i += 256) cur[i] = bucketStart[i] + basemat[row + i];
    __syncthreads();
    int base = blockIdx.x * ECHUNK + t;
#pragma unroll
    for (int k = 0; k < 32; ++k) {
        int i = base + k * 256;
        if (i < e) {
            int d = dst[i];
            int b = d >> BSHIFT;
            int pos = atomicAdd(&cur[b], 1);               // LDS atomic, block-private
            ebuf[pos] = ((unsigned)(d & (BNODES - 1)) << 25) | (unsigned)src[i];
        }
    }
}

// ---- pass 5: one block per bucket -> dst-ordered CSR slice, dinv, graph ranges ----
__global__ void fill2_k(const unsigned int* __restrict__ ebuf,
                        const int* __restrict__ bucketStart,
                        const int* __restrict__ batch, float* __restrict__ dinv,
                        int* __restrict__ start, int* __restrict__ csr,
                        int* __restrict__ gstart, int* __restrict__ gend, int n) {
    __shared__ int scnt[BNODES], sincl[BNODES], scur[BNODES];
    int t = threadIdx.x;
    int b = blockIdx.x;
    int node0 = b << BSHIFT;
    int nNodes = min(BNODES, n - node0);
    if (t < BNODES) scnt[t] = 0;
    int e0 = bucketStart[b], e1 = bucketStart[b + 1];
    __syncthreads();
    for (int i = e0 + t; i < e1; i += 256)
        atomicAdd(&scnt[ebuf[i] >> 25], 1);
    __syncthreads();
    int val = (t < BNODES) ? scnt[t] : 0;
    if (t < BNODES) sincl[t] = val;
    __syncthreads();
    for (int off = 1; off < BNODES; off <<= 1) {
        int tmp = (t >= off && t < BNODES) ? sincl[t - off] : 0;
        __syncthreads();
        if (t < BNODES) sincl[t] += tmp;
        __syncthreads();
    }
    if (t < nNodes) {
        int v = node0 + t;
        int st = e0 + sincl[t] - val;     // exclusive within bucket
        start[v] = st;
        scur[t] = st;
        dinv[v] = rsqrtf((float)(val + 1));
        int g = batch[v];                 // sorted-batch boundary detection
        if (v == 0 || batch[v - 1] != g) gstart[g] = v;
        if (v == n - 1 || batch[v + 1] != g) gend[g] = v + 1;
    }
    __syncthreads();
    for (int i = e0 + t; i < e1; i += 256) {
        unsigned rec = ebuf[i];
        int pos = atomicAdd(&scur[rec >> 25], 1);
        csr[pos] = (int)(rec & 0x1FFFFFFu);   // scatter within L2-local 8 KB slice
    }
}

// ---- dense GEMM  C[n,64] = scale[row] * (A[n,64] @ W[64,64]) ----
__global__ void gemm_k(const float* __restrict__ A, const float* __restrict__ W,
                       const float* __restrict__ scale, float* __restrict__ C, int n) {
    __shared__ float Wl[64 * 64];
    __shared__ float Xl[256];
    int t = threadIdx.x;
#pragma unroll
    for (int i = 0; i < 16; ++i) Wl[t + 256 * i] = W[t + 256 * i];
    long base = (long)blockIdx.x * 256;
    Xl[t] = (base + t < (long)n * NDIM) ? A[base + t] : 0.f;
    __syncthreads();
    int row = t >> 6, col = t & 63;
    float acc = 0.f;
    const float4* Xv = (const float4*)&Xl[row * 64];
#pragma unroll
    for (int k4 = 0; k4 < 16; ++k4) {
        float4 xv = Xv[k4];
        acc += xv.x * Wl[(4 * k4 + 0) * 64 + col];
        acc += xv.y * Wl[(4 * k4 + 1) * 64 + col];
        acc += xv.z * Wl[(4 * k4 + 2) * 64 + col];
        acc += xv.w * Wl[(4 * k4 + 3) * 64 + col];
    }
    int v = blockIdx.x * 4 + row;
    if (v < n) C[(long)v * NDIM + col] = scale[v] * acc;
}

// ---- aggregation: out[v,:] = relu( dinv[v]*(sum_e xws[src_e,:] + xws[v,:]) + b ) ----
// one 64-lane wave per node, lane = dim; unrolled x4 -> 4 gathers in flight
__global__ void agg_k(const float* __restrict__ xws, const float* __restrict__ dinv,
                      const int* __restrict__ start, const int* __restrict__ csr,
                      const float* __restrict__ bias, float* __restrict__ out, int n) {
    int t = threadIdx.x;
    int lane = t & 63;
    int v = blockIdx.x * 4 + (t >> 6);
    if (v >= n) return;
    int s0 = start[v];
    int d0 = start[v + 1] - s0;
    float a0 = 0.f, a1 = 0.f, a2 = 0.f, a3 = 0.f;
    int i = 0;
    for (; i + 4 <= d0; i += 4) {
        int j0 = csr[s0 + i + 0];
        int j1 = csr[s0 + i + 1];
        int j2 = csr[s0 + i + 2];
        int j3 = csr[s0 + i + 3];
        float x0 = xws[(long)j0 * NDIM + lane];
        float x1 = xws[(long)j1 * NDIM + lane];
        float x2 = xws[(long)j2 * NDIM + lane];
        float x3 = xws[(long)j3 * NDIM + lane];
        a0 += x0; a1 += x1; a2 += x2; a3 += x3;
    }
    for (; i < d0; ++i) a0 += xws[(long)csr[s0 + i] * NDIM + lane];
    float acc = (a0 + a1) + (a2 + a3);
    acc += xws[(long)v * NDIM + lane];          // self loop (xws already has one dinv)
    acc = acc * dinv[v] + bias[lane];
    out[(long)v * NDIM + lane] = fmaxf(acc, 0.f);
}

// ---- mean-pool (batch sorted): register accumulate, flush on graph change ----
#define POOL_TILE 256
__global__ void pool_k(const float* __restrict__ h, const int* __restrict__ batch,
                       float* __restrict__ pooled, int n) {
    int t = threadIdx.x;
    int lane = t & 63;
    int sub = t >> 6;                 // 0..3
    int base = blockIdx.x * POOL_TILE;
    int gcur = -1;
    float acc = 0.f;
    for (int k = 0; k < POOL_TILE / 4; ++k) {
        int v = base + sub + 4 * k;   // monotone per thread -> few graph changes
        if (v < n) {
            int g = batch[v];
            if (g != gcur) {
                if (gcur >= 0) atomicAdd(&pooled[gcur * NDIM + lane], acc);
                gcur = g;
                acc = 0.f;
            }
            acc += h[(long)v * NDIM + lane];
        }
    }
    if (gcur >= 0) atomicAdd(&pooled[gcur * NDIM + lane], acc);
}

// ---- head: out[g,c] = (pooled[g,:]/max(cnt,1)) @ Wlin + blin ----
__global__ void final_k(const float* __restrict__ pooled, const int* __restrict__ gstart,
                        const int* __restrict__ gend,
                        const float* __restrict__ Wlin, const float* __restrict__ blin,
                        float* __restrict__ out, int nclass) {
    int t = blockIdx.x * blockDim.x + threadIdx.x;
    if (t >= NGRAPH * nclass) return;
    int g = t / nclass, c = t % nclass;
    float cnt = (float)(gend[g] - gstart[g]);
    float inv = 1.f / fmaxf(cnt, 1.f);
    float acc = 0.f;
    for (int j = 0; j < NDIM; ++j) acc += pooled[g * NDIM + j] * Wlin[j * nclass + c];
    out[t] = acc * inv + blin[c];
}

extern "C" void kernel_launch(void* const* d_in, const int* in_sizes, int n_in,
                              void* d_out, int out_size, void* d_ws, size_t ws_size,
                              hipStream_t stream) {
    const float* x     = (const float*)d_in[0];
    const int*   ei    = (const int*)d_in[1];
    const int*   batch = (const int*)d_in[2];
    const float* W1    = (const float*)d_in[3];
    const float* b1    = (const float*)d_in[4];
    const float* W2    = (const float*)d_in[5];
    const float* b2    = (const float*)d_in[6];
    const float* Wlin  = (const float*)d_in[7];
    const float* blin  = (const float*)d_in[8];
    float* out = (float*)d_out;

    const int N = in_sizes[0] / NDIM;        // 100000
    const int E = in_sizes[1] / 2;           // 1600000
    const int NCLASS = in_sizes[7] / NDIM;   // 10
    const int* src = ei;
    const int* dst = ei + E;
    const int NB   = (N + BNODES - 1) >> BSHIFT;        // 782 buckets (<=1024)
    const int NBLK = (E + ECHUNK - 1) / ECHUNK;         // 196 edge blocks (<=256)

    // ---- workspace carve-out (each 256B-aligned) ----
    size_t o = 0;
    char* wsp = (char*)d_ws;
    auto take = [&](size_t nbytes) -> void* {
        void* p = (void*)(wsp + o);
        o += (nbytes + 255) & ~(size_t)255;
        return p;
    };
    int*   gstart    = (int*)take(NGRAPH * 4);
    int*   gend      = (int*)take(NGRAPH * 4);
    float* pooled    = (float*)take(NGRAPH * NDIM * 4);
    size_t zero_bytes = o;                    // everything above must start at 0
    int*   cntmat   = (int*)take((size_t)NBLK * NB * 4);
    int*   basemat  = (int*)take((size_t)NBLK * NB * 4);
    int*   bucketTot   = (int*)take((size_t)NB * 4);
    int*   bucketStart = (int*)take((size_t)(NB + 1) * 4);
    float* dinv  = (float*)take((size_t)N * 4);
    int*   start = (int*)take((size_t)(N + 1) * 4);
    int*   csr   = (int*)take((size_t)E * 4);
    unsigned int* ebuf = (unsigned int*)take((size_t)E * 4);
    float* xws   = (float*)take((size_t)N * NDIM * 4);
    float* h     = (float*)take((size_t)N * NDIM * 4);
    (void)ws_size;

    hipMemsetAsync(d_ws, 0, zero_bytes, stream);

    int rbl = (N + 3) / 4;                    // 4 nodes per block (gemm/agg)

    // CSR build (deterministic two-pass binning, zero global atomics)
    bincnt_k<<<NBLK, 256, (size_t)NB * 4, stream>>>(dst, cntmat, E, NB);
    colscan_k<<<NB, 256, 0, stream>>>(cntmat, basemat, bucketTot, NBLK, NB);
    bscan_k<<<1, 1024, 0, stream>>>(bucketTot, bucketStart, start, NB, N, E);
    bscatter_k<<<NBLK, 256, (size_t)NB * 4, stream>>>(src, dst, bucketStart, basemat, ebuf, E, NB);
    fill2_k<<<NB, 256, 0, stream>>>(ebuf, bucketStart, batch, dinv, start, csr, gstart, gend, N);

    // layer 1
    gemm_k<<<rbl, 256, 0, stream>>>(x, W1, dinv, xws, N);
    agg_k<<<rbl, 256, 0, stream>>>(xws, dinv, start, csr, b1, h, N);
    // layer 2
    gemm_k<<<rbl, 256, 0, stream>>>(h, W2, dinv, xws, N);
    agg_k<<<rbl, 256, 0, stream>>>(xws, dinv, start, csr, b2, h, N);

    // pooling + head
    pool_k<<<(N + POOL_TILE - 1) / POOL_TILE, 256, 0, stream>>>(h, batch, pooled, N);
    final_k<<<(NGRAPH * NCLASS + 255) / 256, 256, 0, stream>>>(pooled, gstart, gend, Wlin, blin, out, NCLASS);
}